// Round 7
// baseline (239.427 us; speedup 1.0000x reference)
//
#include <hip/hip_runtime.h>
#include <hip/hip_bf16.h>
#include <stdint.h>

// Problem: B=4, C=256, O=256, H=W=64, K=3, K2=9, KK=2304
// ws: xT bf16 NHWC @0 (8388608) | yT @8388608 (8388608) | Wp2 @16777216
//     (1179648) | Bo (+147456)

typedef __bf16 bf16x8 __attribute__((ext_vector_type(8)));
typedef float  f32x4  __attribute__((ext_vector_type(4)));

__device__ __forceinline__ unsigned short f2bfu(float f) {
    union { float f; unsigned u; } v; v.f = f;
    return (unsigned short)((v.u + 0x8000u) >> 16);
}
__device__ __forceinline__ float lo16(unsigned u) {
    union { unsigned u; float f; } v; v.u = u << 16; return v.f;
}
__device__ __forceinline__ float hi16(unsigned u) {
    union { unsigned u; float f; } v; v.u = u & 0xFFFF0000u; return v.f;
}
__device__ __forceinline__ unsigned fbits(float f) {
    union { float f; unsigned u; } v; v.f = f; return v.u;
}
__device__ __forceinline__ unsigned blend2(unsigned u0, unsigned u1, unsigned u2, unsigned u3,
                                           float4 w) {
    float lo = w.x * lo16(u0) + w.y * lo16(u1) + w.z * lo16(u2) + w.w * lo16(u3);
    float hi = w.x * hi16(u0) + w.y * hi16(u1) + w.z * hi16(u2) + w.w * hi16(u3);
    unsigned rl = fbits(lo) + 0x8000u;
    unsigned rh = fbits(hi) + 0x8000u;
    return __builtin_amdgcn_perm(rh, rl, 0x07060302);
}

// ---------------------------------------------------------------------------
// prep: fused {x,y transpose to NHWC bf16} + {packw} + {packow}.
// Bo N-tiles are SPLIT BY OUTPUT TAP: tile0 (n 0..15) = offsets outputs for
// taps 0-4 (local n = 2*tl+comp, 10 valid); tile1 (n 16..31) = taps 5-8.
// ---------------------------------------------------------------------------
__global__ __launch_bounds__(256) void prep_kernel(
    const float* __restrict__ x, const float* __restrict__ y,
    const float* __restrict__ ow, const float* __restrict__ dw,
    unsigned short* __restrict__ xT, unsigned short* __restrict__ yT,
    unsigned short* __restrict__ Wp2, unsigned short* __restrict__ Bo)
{
    __shared__ float tile[64 * 69];
    int blk = blockIdx.x;
    int t = threadIdx.x;
    if (blk < 2048) {
        const float* src = x; unsigned short* dst = xT;
        if (blk >= 1024) { src = y; dst = yT; blk -= 1024; }
        int cq = blk & 3;
        int bh = blk >> 2;
        int w4 = t & 15, cl0 = t >> 4;
        const float* s = src + ((size_t)(bh >> 6) * 256 + cq * 64) * 4096 + (size_t)(bh & 63) * 64;
#pragma unroll
        for (int p = 0; p < 4; ++p) {
            int cl = p * 16 + cl0;
            float4 v = *(const float4*)&s[(size_t)cl * 4096 + w4 * 4];
            tile[(w4 * 4 + 0) * 69 + cl] = v.x;
            tile[(w4 * 4 + 1) * 69 + cl] = v.y;
            tile[(w4 * 4 + 2) * 69 + cl] = v.z;
            tile[(w4 * 4 + 3) * 69 + cl] = v.w;
        }
        __syncthreads();
        unsigned short* d = dst + (size_t)bh * 16384 + cq * 64;
#pragma unroll
        for (int p = 0; p < 4; ++p) {
            int w = p * 16 + cl0;
            float4 v = *(const float4*)&tile[w * 69 + w4 * 4];
            ushort4 r = make_ushort4(f2bfu(v.x), f2bfu(v.y), f2bfu(v.z), f2bfu(v.w));
            *(ushort4*)&d[w * 256 + w4 * 4] = r;
        }
    } else if (blk < 2336) {
        int tid = (blk - 2048) * 256 + t;
        int q8 = tid >> 8;
        int o  = tid & 255;
        int k0 = q8 * 8;
        int tap = k0 >> 8, c0 = k0 & 255;
        const float* s = dw + o * 2304 + c0 * 9 + tap;
        ushort4 r0 = make_ushort4(f2bfu(s[0]), f2bfu(s[9]), f2bfu(s[18]), f2bfu(s[27]));
        ushort4 r1 = make_ushort4(f2bfu(s[36]), f2bfu(s[45]), f2bfu(s[54]), f2bfu(s[63]));
        *(ushort4*)&Wp2[tid * 8 + 0] = r0;
        *(ushort4*)&Wp2[tid * 8 + 4] = r1;
    } else {
        int idx = (blk - 2336) * 256 + t;
        int j = idx & 7;
        int n32 = (idx >> 3) & 31;
        int lq = (idx >> 8) & 3;
        int kg = idx >> 10;
        int k = kg * 32 + lq * 8 + j;
        int tapk = k >> 8, c = k & 255;
        int o = -1;
        if (n32 < 10) o = n32;
        else if (n32 >= 16 && n32 < 24) o = 10 + (n32 - 16);
        float v = (o >= 0) ? ow[o * 2304 + c * 9 + tapk] : 0.f;
        Bo[idx] = f2bfu(v);
    }
}

// ---------------------------------------------------------------------------
// deform: K-SPLIT fused kernel.  Grid 512 = (b,h,ks): ks=0 -> taps 0-4,
// ks=1 -> taps 5-8.  512 thr = 8 waves, each owns N-slice [ns*32,+32), full
// block-K.  Per-CU L2 = 2 blocks x ~1.2 MB (gather + B tap-slice; no
// redundancy anywhere, incl. the offsets prologue which is output-tap-split).
// Tap loop: issue gather jobs 0,1 (t+1) -> MFMA kc0-3 -> commit 0,1 ->
//           issue 2,3 -> MFMA kc4-7 -> commit 2,3 -> barrier (dbuf A).
// Epilogue: unsafeAtomicAdd fp32 partials into zeroed out (ks=0 adds bias).
// LDS 75776: Abuf 2x32768 | pw 5120 | pi 5120 (prologue red overlaps Abufs).
// ---------------------------------------------------------------------------
__global__ __launch_bounds__(512, 4) void deform_kernel(
    const unsigned short* __restrict__ xT,
    const unsigned short* __restrict__ yT,
    const unsigned short* __restrict__ Wp2,
    const unsigned short* __restrict__ Bo,
    const float* __restrict__ ob,
    const float* __restrict__ db,
    float* __restrict__ out)
{
    __shared__ __align__(16) unsigned char smem[75776];
    unsigned short* Abuf0 = (unsigned short*)smem;
    unsigned short* Abuf1 = (unsigned short*)(smem + 32768);
    float*  red    = (float*)smem;                      // 32 tiles x 272 floats
    float4* pw_lds = (float4*)(smem + 65536);           // 5120 B
    int4*   pi_lds = (int4*)(smem + 65536 + 5120);      // 5120 B

    int blk = blockIdx.x;
    int lb = (blk & 7) * 64 + (blk >> 3);               // XCD b-slab swizzle
    int b = lb >> 7, rem = lb & 127, h = rem >> 1, ks = rem & 1;
    int tap0 = ks ? 5 : 0;
    int ntaps = ks ? 4 : 5;
    int t = threadIdx.x;
    int wv = t >> 6, lane = t & 63;
    int ln = lane & 15, lq = lane >> 4;

    const unsigned short* xtb = xT + (size_t)b * (64 * 64 * 256);

    // ============ offsets prologue: this block's taps, N=16 tile ks ============
    {
        f32x4 oacc[4];
#pragma unroll
        for (int m16 = 0; m16 < 4; ++m16) oacc[m16] = (f32x4){0.f, 0.f, 0.f, 0.f};
        for (int u = wv * 9; u < wv * 9 + 9; ++u) {     // 72 units = 9 conv-taps x 8 kc
            int tapk = u >> 3, kc = u & 7;
            int ki = tapk / 3, kj = tapk - ki * 3;
            int hr = h + ki - 1;
            bf16x8 bo = *(const bf16x8*)&Bo[(tapk * 8 + kc) * 1024 + lq * 256 + (ks * 16 + ln) * 8];
#pragma unroll
            for (int m16 = 0; m16 < 4; ++m16) {
                int wr = m16 * 16 + ln + kj - 1;
                bf16x8 af = (bf16x8)(__bf16)0.0f;
                if (hr >= 0 && hr < 64 && wr >= 0 && wr < 64)
                    af = *(const bf16x8*)&yT[((size_t)(b * 64 + hr) * 64 + wr) * 256 + kc * 32 + lq * 8];
                oacc[m16] = __builtin_amdgcn_mfma_f32_16x16x32_bf16(af, bo, oacc[m16], 0, 0, 0);
            }
        }
#pragma unroll
        for (int m16 = 0; m16 < 4; ++m16) {
            float* rz = red + (size_t)(wv * 4 + m16) * 272;
#pragma unroll
            for (int r = 0; r < 4; ++r)
                rz[ln * 17 + lq * 4 + r] = oacc[m16][r];
        }
    }
    __syncthreads();
    // params: ntaps*64 jobs = (tl, pos)
    if (t < ntaps * 64) {
        int tl = t >> 6, pos = t & 63;
        int m16 = pos >> 4, rr = pos & 15;
        int tapg = tap0 + tl;
        float dy = ob[2 * tapg], dx = ob[2 * tapg + 1];
#pragma unroll
        for (int kq = 0; kq < 8; ++kq) {
            const float* rz = red + (size_t)(kq * 4 + m16) * 272;
            dy += rz[(2 * tl) * 17 + rr];
            dx += rz[(2 * tl + 1) * 17 + rr];
        }
        int ki = tapg / 3, kj = tapg - ki * 3;
        float py = (float)(h - 1 + ki) + dy;
        float px = (float)(pos - 1 + kj) + dx;
        float y0 = floorf(py), x0 = floorf(px);
        float wy1 = py - y0, wx1 = px - x0;
        float wy0 = 1.f - wy1, wx0 = 1.f - wx1;
        float y1 = y0 + 1.f, x1 = x0 + 1.f;
        float vy0 = (y0 >= 0.f && y0 <= 63.f) ? 1.f : 0.f;
        float vy1 = (y1 >= 0.f && y1 <= 63.f) ? 1.f : 0.f;
        float vx0 = (x0 >= 0.f && x0 <= 63.f) ? 1.f : 0.f;
        float vx1 = (x1 >= 0.f && x1 <= 63.f) ? 1.f : 0.f;
        int iy0 = (int)fminf(fmaxf(y0, 0.f), 63.f);
        int iy1 = (int)fminf(fmaxf(y1, 0.f), 63.f);
        int ix0 = (int)fminf(fmaxf(x0, 0.f), 63.f);
        int ix1 = (int)fminf(fmaxf(x1, 0.f), 63.f);
        pw_lds[t] = make_float4(wy0 * wx0 * vy0 * vx0, wy0 * wx1 * vy0 * vx1,
                                wy1 * wx0 * vy1 * vx0, wy1 * wx1 * vy1 * vx1);
        pi_lds[t] = make_int4((iy0 * 64 + ix0) * 256, (iy0 * 64 + ix1) * 256,
                              (iy1 * 64 + ix0) * 256, (iy1 * 64 + ix1) * 256);
    }
    __syncthreads();

    // ============ main tap loop ============
    int ns = wv;
    int gr = lane & 31, c0 = gr * 8;
    int posb = wv * 2 + (lane >> 5);          // job pos = posb + j*16, j=0..3

    f32x4 acc[4][2];
#pragma unroll
    for (int ms = 0; ms < 4; ++ms)
#pragma unroll
        for (int nt = 0; nt < 2; ++nt)
            acc[ms][nt] = (f32x4){0.f, 0.f, 0.f, 0.f};

    uint4 ga[2][4]; float4 gw[2];

#define G_ISSUE(TL, J0)                                              \
    _Pragma("unroll")                                                \
    for (int it = 0; it < 2; ++it) {                                 \
        int pos = posb + ((J0) + it) * 16;                           \
        gw[it] = pw_lds[(TL) * 64 + pos];                            \
        int4 p = pi_lds[(TL) * 64 + pos];                            \
        ga[it][0] = *(const uint4*)&xtb[p.x + c0];                   \
        ga[it][1] = *(const uint4*)&xtb[p.y + c0];                   \
        ga[it][2] = *(const uint4*)&xtb[p.z + c0];                   \
        ga[it][3] = *(const uint4*)&xtb[p.w + c0];                   \
    }
#define G_COMMIT(BUF, J0)                                            \
    _Pragma("unroll")                                                \
    for (int it = 0; it < 2; ++it) {                                 \
        int pos = posb + ((J0) + it) * 16;                           \
        uint4 res;                                                   \
        res.x = blend2(ga[it][0].x, ga[it][1].x, ga[it][2].x, ga[it][3].x, gw[it]); \
        res.y = blend2(ga[it][0].y, ga[it][1].y, ga[it][2].y, ga[it][3].y, gw[it]); \
        res.z = blend2(ga[it][0].z, ga[it][1].z, ga[it][2].z, ga[it][3].z, gw[it]); \
        res.w = blend2(ga[it][0].w, ga[it][1].w, ga[it][2].w, ga[it][3].w, gw[it]); \
        *(uint4*)&(BUF)[pos * 256 + (gr ^ (pos & 7)) * 8] = res;     \
    }

    G_ISSUE(0, 0) G_COMMIT(Abuf0, 0)
    G_ISSUE(0, 2) G_COMMIT(Abuf0, 2)
    __syncthreads();

#pragma unroll 1
    for (int tl = 0; tl < ntaps; ++tl) {
        const unsigned short* Ab = (tl & 1) ? Abuf1 : Abuf0;
        unsigned short* Nb = (tl & 1) ? Abuf0 : Abuf1;
        bool more = (tl + 1 < ntaps);
        if (more) { G_ISSUE(tl + 1, 0) }
#pragma unroll
        for (int kc = 0; kc < 4; ++kc) {
            int g = kc * 4 + lq;
            bf16x8 af[4];
#pragma unroll
            for (int ms = 0; ms < 4; ++ms) {
                int row = ms * 16 + ln;
                af[ms] = *(const bf16x8*)&Ab[row * 256 + (g ^ (row & 7)) * 8];
            }
            int kg = (tap0 + tl) * 8 + kc;
            bf16x8 bfr[2];
#pragma unroll
            for (int nt = 0; nt < 2; ++nt)
                bfr[nt] = *(const bf16x8*)&Wp2[((kg * 4 + lq) * 256 + ns * 32 + nt * 16 + ln) * 8];
#pragma unroll
            for (int ms = 0; ms < 4; ++ms)
#pragma unroll
                for (int nt = 0; nt < 2; ++nt)
                    acc[ms][nt] = __builtin_amdgcn_mfma_f32_16x16x32_bf16(af[ms], bfr[nt], acc[ms][nt], 0, 0, 0);
        }
        if (more) { G_COMMIT(Nb, 0) G_ISSUE(tl + 1, 2) }
#pragma unroll
        for (int kc = 4; kc < 8; ++kc) {
            int g = kc * 4 + lq;
            bf16x8 af[4];
#pragma unroll
            for (int ms = 0; ms < 4; ++ms) {
                int row = ms * 16 + ln;
                af[ms] = *(const bf16x8*)&Ab[row * 256 + (g ^ (row & 7)) * 8];
            }
            int kg = (tap0 + tl) * 8 + kc;
            bf16x8 bfr[2];
#pragma unroll
            for (int nt = 0; nt < 2; ++nt)
                bfr[nt] = *(const bf16x8*)&Wp2[((kg * 4 + lq) * 256 + ns * 32 + nt * 16 + ln) * 8];
#pragma unroll
            for (int ms = 0; ms < 4; ++ms)
#pragma unroll
                for (int nt = 0; nt < 2; ++nt)
                    acc[ms][nt] = __builtin_amdgcn_mfma_f32_16x16x32_bf16(af[ms], bfr[nt], acc[ms][nt], 0, 0, 0);
        }
        if (more) { G_COMMIT(Nb, 2) }
        __syncthreads();
    }

    // ============ epilogue: atomic K-reduce into zeroed out ============
#pragma unroll
    for (int nt = 0; nt < 2; ++nt) {
        int o = ns * 32 + nt * 16 + ln;
        float bias = ks ? 0.f : db[o];
        float* op = out + ((size_t)(b * 256 + o)) * 4096 + h * 64;
#pragma unroll
        for (int ms = 0; ms < 4; ++ms) {
            f32x4 a = acc[ms][nt];
#pragma unroll
            for (int r = 0; r < 4; ++r)
                unsafeAtomicAdd(&op[ms * 16 + lq * 4 + r], a[r] + bias);
        }
    }
#undef G_ISSUE
#undef G_COMMIT
}

extern "C" void kernel_launch(void* const* d_in, const int* in_sizes, int n_in,
                              void* d_out, int out_size, void* d_ws, size_t ws_size,
                              hipStream_t stream) {
    const float* x  = (const float*)d_in[0];
    const float* y  = (const float*)d_in[1];
    const float* ow = (const float*)d_in[2];
    const float* ob = (const float*)d_in[3];
    const float* dw = (const float*)d_in[4];
    const float* db = (const float*)d_in[5];
    float* out = (float*)d_out;

    char* ws = (char*)d_ws;
    unsigned short* xT  = (unsigned short*)(ws);
    unsigned short* yT  = (unsigned short*)(ws + 8388608);
    unsigned short* Wp2 = (unsigned short*)(ws + 16777216);
    unsigned short* Bo  = (unsigned short*)(ws + 16777216 + 1179648);

    hipMemsetAsync(out, 0, (size_t)out_size * sizeof(float), stream);
    hipLaunchKernelGGL(prep_kernel, dim3(2624), dim3(256), 0, stream,
                       x, y, ow, dw, xT, yT, Wp2, Bo);
    hipLaunchKernelGGL(deform_kernel, dim3(512), dim3(512), 0, stream,
                       xT, yT, Wp2, Bo, ob, db, out);
}

// Round 8
// 138.511 us; speedup vs baseline: 1.7286x; 1.7286x over previous
//
#include <hip/hip_runtime.h>
#include <hip/hip_bf16.h>
#include <stdint.h>

// Problem: B=4, C=256, O=256, H=W=64, K=3, K2=9, KK=2304
// ws: xT bf16 NHWC @0 (8388608) | yT @8388608 (8388608) | Wp2 @16777216
//     (1179648) | Bo (+147456)

typedef __bf16 bf16x8 __attribute__((ext_vector_type(8)));
typedef float  f32x4  __attribute__((ext_vector_type(4)));

__device__ __forceinline__ unsigned short f2bfu(float f) {
    union { float f; unsigned u; } v; v.f = f;
    return (unsigned short)((v.u + 0x8000u) >> 16);
}
__device__ __forceinline__ float lo16(unsigned u) {
    union { unsigned u; float f; } v; v.u = u << 16; return v.f;
}
__device__ __forceinline__ float hi16(unsigned u) {
    union { unsigned u; float f; } v; v.u = u & 0xFFFF0000u; return v.f;
}
__device__ __forceinline__ unsigned fbits(float f) {
    union { float f; unsigned u; } v; v.f = f; return v.u;
}
__device__ __forceinline__ unsigned blend2(unsigned u0, unsigned u1, unsigned u2, unsigned u3,
                                           float4 w) {
    float lo = w.x * lo16(u0) + w.y * lo16(u1) + w.z * lo16(u2) + w.w * lo16(u3);
    float hi = w.x * hi16(u0) + w.y * hi16(u1) + w.z * hi16(u2) + w.w * hi16(u3);
    unsigned rl = fbits(lo) + 0x8000u;
    unsigned rh = fbits(hi) + 0x8000u;
    return __builtin_amdgcn_perm(rh, rl, 0x07060302);
}

// ---------------------------------------------------------------------------
// prep: fused {x,y transpose to NHWC bf16} + {packw} + {packow(N=32 pad)}.
// ---------------------------------------------------------------------------
__global__ __launch_bounds__(256) void prep_kernel(
    const float* __restrict__ x, const float* __restrict__ y,
    const float* __restrict__ ow, const float* __restrict__ dw,
    unsigned short* __restrict__ xT, unsigned short* __restrict__ yT,
    unsigned short* __restrict__ Wp2, unsigned short* __restrict__ Bo)
{
    __shared__ float tile[64 * 69];
    int blk = blockIdx.x;
    int t = threadIdx.x;
    if (blk < 2048) {
        const float* src = x; unsigned short* dst = xT;
        if (blk >= 1024) { src = y; dst = yT; blk -= 1024; }
        int cq = blk & 3;
        int bh = blk >> 2;
        int w4 = t & 15, cl0 = t >> 4;
        const float* s = src + ((size_t)(bh >> 6) * 256 + cq * 64) * 4096 + (size_t)(bh & 63) * 64;
#pragma unroll
        for (int p = 0; p < 4; ++p) {
            int cl = p * 16 + cl0;
            float4 v = *(const float4*)&s[(size_t)cl * 4096 + w4 * 4];
            tile[(w4 * 4 + 0) * 69 + cl] = v.x;
            tile[(w4 * 4 + 1) * 69 + cl] = v.y;
            tile[(w4 * 4 + 2) * 69 + cl] = v.z;
            tile[(w4 * 4 + 3) * 69 + cl] = v.w;
        }
        __syncthreads();
        unsigned short* d = dst + (size_t)bh * 16384 + cq * 64;
#pragma unroll
        for (int p = 0; p < 4; ++p) {
            int w = p * 16 + cl0;
            float4 v = *(const float4*)&tile[w * 69 + w4 * 4];
            ushort4 r = make_ushort4(f2bfu(v.x), f2bfu(v.y), f2bfu(v.z), f2bfu(v.w));
            *(ushort4*)&d[w * 256 + w4 * 4] = r;
        }
    } else if (blk < 2336) {
        int tid = (blk - 2048) * 256 + t;
        int q8 = tid >> 8;
        int o  = tid & 255;
        int k0 = q8 * 8;
        int tap = k0 >> 8, c0 = k0 & 255;
        const float* s = dw + o * 2304 + c0 * 9 + tap;
        ushort4 r0 = make_ushort4(f2bfu(s[0]), f2bfu(s[9]), f2bfu(s[18]), f2bfu(s[27]));
        ushort4 r1 = make_ushort4(f2bfu(s[36]), f2bfu(s[45]), f2bfu(s[54]), f2bfu(s[63]));
        *(ushort4*)&Wp2[tid * 8 + 0] = r0;
        *(ushort4*)&Wp2[tid * 8 + 4] = r1;
    } else {
        int idx = (blk - 2336) * 256 + t;
        int j = idx & 7;
        int n = (idx >> 3) & 31;
        int lq = (idx >> 8) & 3;
        int kg = idx >> 10;
        int k = kg * 32 + lq * 8 + j;
        int tap = k >> 8, c = k & 255;
        float v = (n < 18) ? ow[n * 2304 + c * 9 + tap] : 0.f;
        Bo[idx] = f2bfu(v);
    }
}

// ---------------------------------------------------------------------------
// deform: fused offsets + implicit GEMM.  Grid 512 = (b,h,mh): M=32 (w in
// [mh*32,+32)), N=256, K=2304 (all 9 taps).  512 thr = 8 waves, each owns
// N-slice [ns*32,+32), FULL K -> no cross-wave/block K-reduce, direct store.
// Prologue: offsets conv for this block's 32 positions (waves = K-eighths,
//   partials -> red LDS -> bilinear params in pw/pi LDS).
// Tap loop (dbuf A, 1 barrier/tap): issue BOTH gather jobs for tap+1 ->
//   MFMA kc0-3 -> commit job0 -> MFMA kc4-7 -> commit job1 -> barrier.
//   (job1 load->use distance = 32 MFMAs ~ L2 latency.)
// LDS 46080: Abuf 2x16384 | red 34816 (overlap, prologue only) | pw 4608
//   @36864 | pi 4608 @41472.  2-3 blocks/CU.
// ---------------------------------------------------------------------------
__global__ __launch_bounds__(512, 4) void deform_kernel(
    const unsigned short* __restrict__ xT,
    const unsigned short* __restrict__ yT,
    const unsigned short* __restrict__ Wp2,
    const unsigned short* __restrict__ Bo,
    const float* __restrict__ ob,
    const float* __restrict__ db,
    float* __restrict__ out)
{
    __shared__ __align__(16) unsigned char smem[46080];
    unsigned short* Abuf0 = (unsigned short*)smem;
    unsigned short* Abuf1 = (unsigned short*)(smem + 16384);
    float*  red    = (float*)smem;                      // 16 tiles x 544 floats
    float4* pw_lds = (float4*)(smem + 36864);           // 288 x 16B
    int4*   pi_lds = (int4*)(smem + 36864 + 4608);      // 288 x 16B

    int blk = blockIdx.x;
    int lb = (blk & 7) * 64 + (blk >> 3);               // XCD b-slab swizzle
    int b = lb >> 7, rem = lb & 127, h = rem >> 1, mh = rem & 1;
    int t = threadIdx.x;
    int wv = t >> 6, lane = t & 63;
    int ln = lane & 15, lq = lane >> 4;

    const unsigned short* xtb = xT + (size_t)b * (64 * 64 * 256);

    // ============ offsets prologue: 32 positions, waves = K-eighths ============
    {
        f32x4 oacc[2][2];
#pragma unroll
        for (int m16 = 0; m16 < 2; ++m16)
#pragma unroll
            for (int nt = 0; nt < 2; ++nt)
                oacc[m16][nt] = (f32x4){0.f, 0.f, 0.f, 0.f};
        for (int u = wv * 9; u < wv * 9 + 9; ++u) {     // 72 units = 9 taps x 8 kc
            int tapk = u >> 3, kc = u & 7;
            int ki = tapk / 3, kj = tapk - ki * 3;
            int hr = h + ki - 1;
            bf16x8 b0 = *(const bf16x8*)&Bo[(tapk * 8 + kc) * 1024 + lq * 256 + ln * 8];
            bf16x8 b1 = *(const bf16x8*)&Bo[(tapk * 8 + kc) * 1024 + lq * 256 + (16 + ln) * 8];
#pragma unroll
            for (int m16 = 0; m16 < 2; ++m16) {
                int wr = mh * 32 + m16 * 16 + ln + kj - 1;
                bf16x8 af = (bf16x8)(__bf16)0.0f;
                if (hr >= 0 && hr < 64 && wr >= 0 && wr < 64)
                    af = *(const bf16x8*)&yT[((size_t)(b * 64 + hr) * 64 + wr) * 256 + kc * 32 + lq * 8];
                oacc[m16][0] = __builtin_amdgcn_mfma_f32_16x16x32_bf16(af, b0, oacc[m16][0], 0, 0, 0);
                oacc[m16][1] = __builtin_amdgcn_mfma_f32_16x16x32_bf16(af, b1, oacc[m16][1], 0, 0, 0);
            }
        }
#pragma unroll
        for (int m16 = 0; m16 < 2; ++m16) {
            float* rz = red + (size_t)(wv * 2 + m16) * 544;
#pragma unroll
            for (int nt = 0; nt < 2; ++nt) {
                int o_l = nt * 16 + ln;
#pragma unroll
                for (int r = 0; r < 4; ++r)
                    rz[o_l * 17 + lq * 4 + r] = oacc[m16][nt][r];
            }
        }
    }
    __syncthreads();
    // params: 288 jobs = (tap, local pos)
    if (t < 288) {
        int tl = t >> 5, pos = t & 31;
        int m16p = pos >> 4, rr = pos & 15;
        float dy = ob[2 * tl], dx = ob[2 * tl + 1];
#pragma unroll
        for (int kq = 0; kq < 8; ++kq) {
            const float* rz = red + (size_t)(kq * 2 + m16p) * 544;
            dy += rz[(2 * tl) * 17 + rr];
            dx += rz[(2 * tl + 1) * 17 + rr];
        }
        int pos_g = mh * 32 + pos;
        int ki = tl / 3, kj = tl - ki * 3;
        float py = (float)(h - 1 + ki) + dy;
        float px = (float)(pos_g - 1 + kj) + dx;
        float y0 = floorf(py), x0 = floorf(px);
        float wy1 = py - y0, wx1 = px - x0;
        float wy0 = 1.f - wy1, wx0 = 1.f - wx1;
        float y1 = y0 + 1.f, x1 = x0 + 1.f;
        float vy0 = (y0 >= 0.f && y0 <= 63.f) ? 1.f : 0.f;
        float vy1 = (y1 >= 0.f && y1 <= 63.f) ? 1.f : 0.f;
        float vx0 = (x0 >= 0.f && x0 <= 63.f) ? 1.f : 0.f;
        float vx1 = (x1 >= 0.f && x1 <= 63.f) ? 1.f : 0.f;
        int iy0 = (int)fminf(fmaxf(y0, 0.f), 63.f);
        int iy1 = (int)fminf(fmaxf(y1, 0.f), 63.f);
        int ix0 = (int)fminf(fmaxf(x0, 0.f), 63.f);
        int ix1 = (int)fminf(fmaxf(x1, 0.f), 63.f);
        pw_lds[t] = make_float4(wy0 * wx0 * vy0 * vx0, wy0 * wx1 * vy0 * vx1,
                                wy1 * wx0 * vy1 * vx0, wy1 * wx1 * vy1 * vx1);
        pi_lds[t] = make_int4((iy0 * 64 + ix0) * 256, (iy0 * 64 + ix1) * 256,
                              (iy1 * 64 + ix0) * 256, (iy1 * 64 + ix1) * 256);
    }
    __syncthreads();

    // ============ main tap loop ============
    int ns = wv;
    int gr = t & 31, c0 = gr * 8;
    int posb = (t >> 5) & 15;                 // job pos = posb + it*16

    f32x4 acc[2][2];
#pragma unroll
    for (int ms = 0; ms < 2; ++ms)
#pragma unroll
        for (int nt = 0; nt < 2; ++nt)
            acc[ms][nt] = (f32x4){0.f, 0.f, 0.f, 0.f};

    uint4 ga[2][4]; float4 gw[2];

#define G_ISSUE(TL)                                                  \
    _Pragma("unroll")                                                \
    for (int it = 0; it < 2; ++it) {                                 \
        int pos = posb + it * 16;                                    \
        gw[it] = pw_lds[(TL) * 32 + pos];                            \
        int4 p = pi_lds[(TL) * 32 + pos];                            \
        ga[it][0] = *(const uint4*)&xtb[p.x + c0];                   \
        ga[it][1] = *(const uint4*)&xtb[p.y + c0];                   \
        ga[it][2] = *(const uint4*)&xtb[p.z + c0];                   \
        ga[it][3] = *(const uint4*)&xtb[p.w + c0];                   \
    }
#define G_COMMIT(BUF, IT)                                            \
    {                                                                \
        int pos = posb + (IT) * 16;                                  \
        uint4 res;                                                   \
        res.x = blend2(ga[IT][0].x, ga[IT][1].x, ga[IT][2].x, ga[IT][3].x, gw[IT]); \
        res.y = blend2(ga[IT][0].y, ga[IT][1].y, ga[IT][2].y, ga[IT][3].y, gw[IT]); \
        res.z = blend2(ga[IT][0].z, ga[IT][1].z, ga[IT][2].z, ga[IT][3].z, gw[IT]); \
        res.w = blend2(ga[IT][0].w, ga[IT][1].w, ga[IT][2].w, ga[IT][3].w, gw[IT]); \
        *(uint4*)&(BUF)[pos * 256 + (gr ^ (pos & 7)) * 8] = res;     \
    }

    G_ISSUE(0)
    G_COMMIT(Abuf0, 0)
    G_COMMIT(Abuf0, 1)
    __syncthreads();

#pragma unroll 1
    for (int tl = 0; tl < 9; ++tl) {
        const unsigned short* Ab = (tl & 1) ? Abuf1 : Abuf0;
        unsigned short* Nb = (tl & 1) ? Abuf0 : Abuf1;
        bool more = (tl < 8);
        if (more) { G_ISSUE(tl + 1) }
#pragma unroll
        for (int kc = 0; kc < 4; ++kc) {
            int g = kc * 4 + lq;
            bf16x8 af[2];
#pragma unroll
            for (int ms = 0; ms < 2; ++ms) {
                int row = ms * 16 + ln;
                af[ms] = *(const bf16x8*)&Ab[row * 256 + (g ^ (row & 7)) * 8];
            }
            int kg = tl * 8 + kc;
            bf16x8 bfr[2];
#pragma unroll
            for (int nt = 0; nt < 2; ++nt)
                bfr[nt] = *(const bf16x8*)&Wp2[((kg * 4 + lq) * 256 + ns * 32 + nt * 16 + ln) * 8];
#pragma unroll
            for (int ms = 0; ms < 2; ++ms)
#pragma unroll
                for (int nt = 0; nt < 2; ++nt)
                    acc[ms][nt] = __builtin_amdgcn_mfma_f32_16x16x32_bf16(af[ms], bfr[nt], acc[ms][nt], 0, 0, 0);
        }
        if (more) { G_COMMIT(Nb, 0) }
#pragma unroll
        for (int kc = 4; kc < 8; ++kc) {
            int g = kc * 4 + lq;
            bf16x8 af[2];
#pragma unroll
            for (int ms = 0; ms < 2; ++ms) {
                int row = ms * 16 + ln;
                af[ms] = *(const bf16x8*)&Ab[row * 256 + (g ^ (row & 7)) * 8];
            }
            int kg = tl * 8 + kc;
            bf16x8 bfr[2];
#pragma unroll
            for (int nt = 0; nt < 2; ++nt)
                bfr[nt] = *(const bf16x8*)&Wp2[((kg * 4 + lq) * 256 + ns * 32 + nt * 16 + ln) * 8];
#pragma unroll
            for (int ms = 0; ms < 2; ++ms)
#pragma unroll
                for (int nt = 0; nt < 2; ++nt)
                    acc[ms][nt] = __builtin_amdgcn_mfma_f32_16x16x32_bf16(af[ms], bfr[nt], acc[ms][nt], 0, 0, 0);
        }
        if (more) { G_COMMIT(Nb, 1) }
        __syncthreads();
    }
#undef G_ISSUE
#undef G_COMMIT

    // ============ epilogue: full-K acc -> bias + direct store ============
#pragma unroll
    for (int nt = 0; nt < 2; ++nt) {
        int o = ns * 32 + nt * 16 + ln;
        float bias = db[o];
        float* op = out + ((size_t)(b * 256 + o)) * 4096 + h * 64 + mh * 32;
#pragma unroll
        for (int ms = 0; ms < 2; ++ms) {
            f32x4 a = acc[ms][nt];
            float4 st = make_float4(a[0] + bias, a[1] + bias, a[2] + bias, a[3] + bias);
            *(float4*)&op[ms * 16 + lq * 4] = st;
        }
    }
}

extern "C" void kernel_launch(void* const* d_in, const int* in_sizes, int n_in,
                              void* d_out, int out_size, void* d_ws, size_t ws_size,
                              hipStream_t stream) {
    const float* x  = (const float*)d_in[0];
    const float* y  = (const float*)d_in[1];
    const float* ow = (const float*)d_in[2];
    const float* ob = (const float*)d_in[3];
    const float* dw = (const float*)d_in[4];
    const float* db = (const float*)d_in[5];
    float* out = (float*)d_out;

    char* ws = (char*)d_ws;
    unsigned short* xT  = (unsigned short*)(ws);
    unsigned short* yT  = (unsigned short*)(ws + 8388608);
    unsigned short* Wp2 = (unsigned short*)(ws + 16777216);
    unsigned short* Bo  = (unsigned short*)(ws + 16777216 + 1179648);

    hipLaunchKernelGGL(prep_kernel, dim3(2624), dim3(256), 0, stream,
                       x, y, ow, dw, xT, yT, Wp2, Bo);
    hipLaunchKernelGGL(deform_kernel, dim3(512), dim3(512), 0, stream,
                       xT, yT, Wp2, Bo, ob, db, out);
}